// Round 5
// baseline (188.726 us; speedup 1.0000x reference)
//
#include <hip/hip_runtime.h>
#include <cstdint>
#include <cstddef>

#define D 128
#define ALPHA 0.2f

typedef __attribute__((ext_vector_type(8))) short short8_t;   // 8 x bf16
typedef __attribute__((ext_vector_type(4))) float f32x4_t;

static __device__ __forceinline__ ushort f2bf(float f) {
    union { float f; uint32_t u; } v; v.f = f;
    uint32_t r = (v.u + 0x7FFFu + ((v.u >> 16) & 1u)) >> 16;
    return (ushort)r;
}

// ---------------------------------------------------------------------------
// Kernel 0: W [128][128] fp32 -> Wt [n][k] bf16 (transposed)
// ---------------------------------------------------------------------------
__global__ __launch_bounds__(256) void w_prep_kernel(const float* __restrict__ W,
                                                     ushort* __restrict__ Wt) {
    int idx = blockIdx.x * 256 + threadIdx.x;   // 0..16383
    int k = idx >> 7;
    int n = idx & 127;
    Wt[n * 128 + k] = f2bf(W[idx]);
}

// ---------------------------------------------------------------------------
// Kernel 1: Hb = bf16(A @ W) via bf16 MFMA (fp32 accum).
// Block 256 = 4 waves; tile 64 rows x 128 cols.
// ---------------------------------------------------------------------------
__global__ __launch_bounds__(256) void gemm_h_kernel(const float* __restrict__ A,
                                                     const ushort* __restrict__ Wt,
                                                     ushort* __restrict__ Hb,
                                                     int N) {
    __shared__ ushort Alds[64][136];
    const int tid = threadIdx.x;
    const int r0 = blockIdx.x * 64;

#pragma unroll
    for (int it = 0; it < 8; ++it) {
        int idx = it * 256 + tid;          // 0..2047
        int r = idx >> 5;
        int c4 = (idx & 31) * 4;
        float4 v = make_float4(0.f, 0.f, 0.f, 0.f);
        if (r0 + r < N) v = *(const float4*)(A + (size_t)(r0 + r) * D + c4);
        ushort4 b;
        b.x = f2bf(v.x); b.y = f2bf(v.y); b.z = f2bf(v.z); b.w = f2bf(v.w);
        *(ushort4*)&Alds[r][c4] = b;
    }
    __syncthreads();

    const int lane = tid & 63;
    const int w = tid >> 6;
    const int wm = w >> 1;
    const int wn = w & 1;
    const int l15 = lane & 15;
    const int koff = (lane >> 4) * 8;

    f32x4_t acc[2][4];
#pragma unroll
    for (int mt = 0; mt < 2; ++mt)
#pragma unroll
        for (int nt = 0; nt < 4; ++nt) acc[mt][nt] = (f32x4_t){0.f, 0.f, 0.f, 0.f};

    const int arow = wm * 32 + l15;
#pragma unroll
    for (int kk = 0; kk < 4; ++kk) {
        short8_t am0 = *(const short8_t*)&Alds[arow][kk * 32 + koff];
        short8_t am1 = *(const short8_t*)&Alds[arow + 16][kk * 32 + koff];
        short8_t bn[4];
#pragma unroll
        for (int nt = 0; nt < 4; ++nt)
            bn[nt] = *(const short8_t*)(Wt + (size_t)(wn * 64 + nt * 16 + l15) * 128 + kk * 32 + koff);
#pragma unroll
        for (int nt = 0; nt < 4; ++nt) {
            acc[0][nt] = __builtin_amdgcn_mfma_f32_16x16x32_bf16(am0, bn[nt], acc[0][nt], 0, 0, 0);
            acc[1][nt] = __builtin_amdgcn_mfma_f32_16x16x32_bf16(am1, bn[nt], acc[1][nt], 0, 0, 0);
        }
    }

    const int crow = (lane >> 4) * 4;
#pragma unroll
    for (int mt = 0; mt < 2; ++mt)
#pragma unroll
        for (int nt = 0; nt < 4; ++nt)
#pragma unroll
            for (int r = 0; r < 4; ++r) {
                int row = r0 + wm * 32 + mt * 16 + crow + r;
                if (row < N)
                    Hb[(size_t)row * D + wn * 64 + nt * 16 + l15] = f2bf(acc[mt][nt][r]);
            }
}

// ---------------------------------------------------------------------------
// CSR construction: histogram -> hierarchical exclusive scan -> scatter
// ---------------------------------------------------------------------------
__global__ __launch_bounds__(256) void hist_kernel(const int* __restrict__ src,
                                                   int* __restrict__ counts, int E) {
    int i = blockIdx.x * blockDim.x + threadIdx.x;
    int stride = gridDim.x * blockDim.x;
    for (; i < E; i += stride) atomicAdd(&counts[src[i]], 1);
}

__global__ __launch_bounds__(256) void scan_partial_kernel(const int* __restrict__ counts,
                                                           int* __restrict__ blocksum, int N) {
    __shared__ int wsum[4];
    int tid = threadIdx.x;
    int i = blockIdx.x * 256 + tid;
    int x = (i < N) ? counts[i] : 0;
#pragma unroll
    for (int off = 32; off > 0; off >>= 1) x += __shfl_down(x, off);
    if ((tid & 63) == 0) wsum[tid >> 6] = x;
    __syncthreads();
    if (tid == 0) blocksum[blockIdx.x] = wsum[0] + wsum[1] + wsum[2] + wsum[3];
}

__global__ __launch_bounds__(256) void scan_top_kernel(const int* __restrict__ blocksum,
                                                       int* __restrict__ blockoff, int nblk) {
    __shared__ int wsum[4];
    int tid = threadIdx.x;
    int lane = tid & 63, w = tid >> 6;
    int v = (tid < nblk) ? blocksum[tid] : 0;
    int x = v;
#pragma unroll
    for (int off = 1; off < 64; off <<= 1) {
        int y = __shfl_up(x, off);
        if (lane >= off) x += y;
    }
    if (lane == 63) wsum[w] = x;
    __syncthreads();
    int woff = 0;
    for (int i = 0; i < w; ++i) woff += wsum[i];
    if (tid < nblk) blockoff[tid] = woff + x - v;
}

__global__ __launch_bounds__(256) void scan_final_kernel(const int* __restrict__ counts,
                                                         const int* __restrict__ blockoff,
                                                         int* __restrict__ starts,
                                                         int* __restrict__ cursor, int N) {
    __shared__ int wsum[4];
    int tid = threadIdx.x;
    int lane = tid & 63, w = tid >> 6;
    int i = blockIdx.x * 256 + tid;
    int c = (i < N) ? counts[i] : 0;
    int x = c;
#pragma unroll
    for (int off = 1; off < 64; off <<= 1) {
        int y = __shfl_up(x, off);
        if (lane >= off) x += y;
    }
    if (lane == 63) wsum[w] = x;
    __syncthreads();
    int woff = blockoff[blockIdx.x];
    for (int j = 0; j < w; ++j) woff += wsum[j];
    int pre = woff + x - c;
    if (i < N) {
        starts[i] = pre;
        cursor[i] = pre;
        if (i == N - 1) starts[N] = pre + c;
    }
}

__global__ __launch_bounds__(256) void scatter_kernel(const int* __restrict__ src,
                                                      const int* __restrict__ dst,
                                                      int* __restrict__ cursor,
                                                      int* __restrict__ dsts_sorted, int E) {
    int i = blockIdx.x * blockDim.x + threadIdx.x;
    int stride = gridDim.x * blockDim.x;
    for (; i < E; i += stride) {
        int pos = atomicAdd(&cursor[src[i]], 1);
        dsts_sorted[pos] = dst[i];
    }
}

// ---------------------------------------------------------------------------
// Node kernel: one wave per node; TWO edges per wave-instruction.
// Lanes 0-31 process even edges, 32-63 odd edges; lane owns 4 features as
// packed bf16x4 (8B gather). Invalid edges get p=-1e30 -> exp=0 -> unmasked
// accumulate. Butterfly reduce folds within 32-lane halves.
// ---------------------------------------------------------------------------
__global__ __launch_bounds__(256) void node_kernel(const ushort* __restrict__ Hb,
                                                   const int* __restrict__ starts,
                                                   const int* __restrict__ dsts_sorted,
                                                   const float* __restrict__ a,
                                                   float* __restrict__ out, int N) {
    int node = (blockIdx.x << 2) + (threadIdx.x >> 6);
    if (node >= N) return;
    const int lane = threadIdx.x & 63;
    const int q = lane & 31;
    const int h = lane >> 5;

    const int beg = starts[node];
    const int end = starts[node + 1];

    // own row, features q*4 .. q*4+3
    uint2 hsu = *(const uint2*)(Hb + ((uint)node << 7) + (q << 2));
    float hs0 = __uint_as_float(hsu.x << 16);
    float hs1 = __uint_as_float(hsu.x & 0xffff0000u);
    float hs2 = __uint_as_float(hsu.y << 16);
    float hs3 = __uint_as_float(hsu.y & 0xffff0000u);
    float4 av = *(const float4*)(a + (q << 2));

    float acc0 = 0.f, acc1 = 0.f, acc2 = 0.f, acc3 = 0.f, rs = 0.f;

    const int brev[16] = {0, 8, 4, 12, 2, 10, 6, 14, 1, 9, 5, 13, 3, 11, 7, 15};

    for (int base = beg; base < end; base += 64) {
        int n64 = min(64, end - base);
        int dt = (lane < n64) ? dsts_sorted[base + lane] : 0;

        for (int c = 0; c < n64; c += 32) {
            // reg j in half h handles edge (c + 2j + h)
            const int erel = c + h;
            uint2 hv[16];
            float p[16];
#pragma unroll
            for (int j = 0; j < 16; ++j) {
                int dj = __shfl(dt, erel + 2 * j);
                hv[j] = *(const uint2*)(Hb + ((uint)dj << 7) + (q << 2));
            }
#pragma unroll
            for (int j = 0; j < 16; ++j) {
                float f0 = __uint_as_float(hv[j].x << 16);
                float f1 = __uint_as_float(hv[j].x & 0xffff0000u);
                float f2 = __uint_as_float(hv[j].y << 16);
                float f3 = __uint_as_float(hv[j].y & 0xffff0000u);
                float s0 = hs0 + f0, s1 = hs1 + f1, s2 = hs2 + f2, s3 = hs3 + f3;
                s0 = fmaxf(s0, ALPHA * s0);
                s1 = fmaxf(s1, ALPHA * s1);
                s2 = fmaxf(s2, ALPHA * s2);
                s3 = fmaxf(s3, ALPHA * s3);
                float pj = fmaf(s0, av.x, fmaf(s1, av.y, fmaf(s2, av.z, s3 * av.w)));
                p[j] = (erel + 2 * j < n64) ? pj : -1e30f;
            }
            // butterfly multi-reduce within each 32-lane half
            {
                bool hi = q & 1;
#pragma unroll
                for (int i = 0; i < 8; ++i) {
                    float send = hi ? p[i] : p[i + 8];
                    float recv = __shfl_xor(send, 1);
                    p[i] = (hi ? p[i + 8] : p[i]) + recv;
                }
                hi = q & 2;
#pragma unroll
                for (int i = 0; i < 4; ++i) {
                    float send = hi ? p[i] : p[i + 4];
                    float recv = __shfl_xor(send, 2);
                    p[i] = (hi ? p[i + 4] : p[i]) + recv;
                }
                hi = q & 4;
#pragma unroll
                for (int i = 0; i < 2; ++i) {
                    float send = hi ? p[i] : p[i + 2];
                    float recv = __shfl_xor(send, 4);
                    p[i] = (hi ? p[i + 2] : p[i]) + recv;
                }
                hi = q & 8;
                {
                    float send = hi ? p[0] : p[1];
                    float recv = __shfl_xor(send, 8);
                    p[0] = (hi ? p[1] : p[0]) + recv;
                }
                p[0] += __shfl_xor(p[0], 16);
            }
            // lane q (in half h) holds dot for edge (c + 2*brev4(q&15) + h)
            float e = __expf(p[0]);
            const int l32 = lane & 32;
#pragma unroll
            for (int j = 0; j < 16; ++j) {
                float ej = __shfl(e, l32 + brev[j]);
                float f0 = __uint_as_float(hv[j].x << 16);
                float f1 = __uint_as_float(hv[j].x & 0xffff0000u);
                float f2 = __uint_as_float(hv[j].y << 16);
                float f3 = __uint_as_float(hv[j].y & 0xffff0000u);
                acc0 = fmaf(ej, f0, acc0);
                acc1 = fmaf(ej, f1, acc1);
                acc2 = fmaf(ej, f2, acc2);
                acc3 = fmaf(ej, f3, acc3);
                rs += ej;
            }
        }
    }

    // fold the two halves
    acc0 += __shfl_xor(acc0, 32);
    acc1 += __shfl_xor(acc1, 32);
    acc2 += __shfl_xor(acc2, 32);
    acc3 += __shfl_xor(acc3, 32);
    rs   += __shfl_xor(rs, 32);

    if (h == 0) {
        float inv = 1.0f / rs;
        float4 o;
        o.x = fmaxf(acc0 * inv, 0.f);
        o.y = fmaxf(acc1 * inv, 0.f);
        o.z = fmaxf(acc2 * inv, 0.f);
        o.w = fmaxf(acc3 * inv, 0.f);
        *(float4*)(out + ((size_t)node << 7) + (q << 2)) = o;
    }
}

extern "C" void kernel_launch(void* const* d_in, const int* in_sizes, int n_in,
                              void* d_out, int out_size, void* d_ws, size_t ws_size,
                              hipStream_t stream) {
    const float* inputs = (const float*)d_in[0];
    const int* edge = (const int*)d_in[1];
    const float* W = (const float*)d_in[2];
    const float* a = (const float*)d_in[3];
    float* out = (float*)d_out;

    const int N = in_sizes[0] / D;   // 50000
    const int E = in_sizes[1] / 2;   // 800000

    const int* src = edge;
    const int* dst = edge + E;

    // ws layout
    ushort* wt = (ushort*)d_ws;                      // [128*128] bf16
    ushort* hb = wt + 128 * 128;                     // [N*128] bf16
    int* counts = (int*)(hb + (size_t)N * D);        // [N]
    int* starts = counts + N;                        // [N+1]
    int* cursor = starts + N + 1;                    // [N]
    int* blocksum = cursor + N;                      // [256]
    int* blockoff = blocksum + 256;                  // [256]
    int* dsts_sorted = blockoff + 256;               // [E]

    const int nblk = (N + 255) / 256;                // 196

    hipMemsetAsync(counts, 0, (size_t)N * sizeof(int), stream);

    w_prep_kernel<<<64, 256, 0, stream>>>(W, wt);
    gemm_h_kernel<<<(N + 63) / 64, 256, 0, stream>>>(inputs, wt, hb, N);
    hist_kernel<<<1024, 256, 0, stream>>>(src, counts, E);
    scan_partial_kernel<<<nblk, 256, 0, stream>>>(counts, blocksum, N);
    scan_top_kernel<<<1, 256, 0, stream>>>(blocksum, blockoff, nblk);
    scan_final_kernel<<<nblk, 256, 0, stream>>>(counts, blockoff, starts, cursor, N);
    scatter_kernel<<<1024, 256, 0, stream>>>(src, dst, cursor, dsts_sorted, E);
    node_kernel<<<(N + 3) / 4, 256, 0, stream>>>(hb, starts, dsts_sorted, a, out, N);
}

// Round 6
// 163.506 us; speedup vs baseline: 1.1542x; 1.1542x over previous
//
#include <hip/hip_runtime.h>
#include <cstdint>
#include <cstddef>

#define D 128
#define ALPHA 0.2f

typedef __attribute__((ext_vector_type(8))) short short8_t;   // 8 x bf16
typedef __attribute__((ext_vector_type(4))) float f32x4_t;

static __device__ __forceinline__ ushort f2bf(float f) {
    union { float f; uint32_t u; } v; v.f = f;
    uint32_t r = (v.u + 0x7FFFu + ((v.u >> 16) & 1u)) >> 16;
    return (ushort)r;
}

// ---------------------------------------------------------------------------
// Kernel 0: W [128][128] fp32 -> Wt [n][k] bf16 (transposed)
// ---------------------------------------------------------------------------
__global__ __launch_bounds__(256) void w_prep_kernel(const float* __restrict__ W,
                                                     ushort* __restrict__ Wt) {
    int idx = blockIdx.x * 256 + threadIdx.x;   // 0..16383
    int k = idx >> 7;
    int n = idx & 127;
    Wt[n * 128 + k] = f2bf(W[idx]);
}

// ---------------------------------------------------------------------------
// Kernel 1: Hb = bf16(A @ W) via bf16 MFMA (fp32 accum).
// ---------------------------------------------------------------------------
__global__ __launch_bounds__(256) void gemm_h_kernel(const float* __restrict__ A,
                                                     const ushort* __restrict__ Wt,
                                                     ushort* __restrict__ Hb,
                                                     int N) {
    __shared__ ushort Alds[64][136];
    const int tid = threadIdx.x;
    const int r0 = blockIdx.x * 64;

#pragma unroll
    for (int it = 0; it < 8; ++it) {
        int idx = it * 256 + tid;          // 0..2047
        int r = idx >> 5;
        int c4 = (idx & 31) * 4;
        float4 v = make_float4(0.f, 0.f, 0.f, 0.f);
        if (r0 + r < N) v = *(const float4*)(A + (size_t)(r0 + r) * D + c4);
        ushort4 b;
        b.x = f2bf(v.x); b.y = f2bf(v.y); b.z = f2bf(v.z); b.w = f2bf(v.w);
        *(ushort4*)&Alds[r][c4] = b;
    }
    __syncthreads();

    const int lane = tid & 63;
    const int w = tid >> 6;
    const int wm = w >> 1;
    const int wn = w & 1;
    const int l15 = lane & 15;
    const int koff = (lane >> 4) * 8;

    f32x4_t acc[2][4];
#pragma unroll
    for (int mt = 0; mt < 2; ++mt)
#pragma unroll
        for (int nt = 0; nt < 4; ++nt) acc[mt][nt] = (f32x4_t){0.f, 0.f, 0.f, 0.f};

    const int arow = wm * 32 + l15;
#pragma unroll
    for (int kk = 0; kk < 4; ++kk) {
        short8_t am0 = *(const short8_t*)&Alds[arow][kk * 32 + koff];
        short8_t am1 = *(const short8_t*)&Alds[arow + 16][kk * 32 + koff];
        short8_t bn[4];
#pragma unroll
        for (int nt = 0; nt < 4; ++nt)
            bn[nt] = *(const short8_t*)(Wt + (size_t)(wn * 64 + nt * 16 + l15) * 128 + kk * 32 + koff);
#pragma unroll
        for (int nt = 0; nt < 4; ++nt) {
            acc[0][nt] = __builtin_amdgcn_mfma_f32_16x16x32_bf16(am0, bn[nt], acc[0][nt], 0, 0, 0);
            acc[1][nt] = __builtin_amdgcn_mfma_f32_16x16x32_bf16(am1, bn[nt], acc[1][nt], 0, 0, 0);
        }
    }

    const int crow = (lane >> 4) * 4;
#pragma unroll
    for (int mt = 0; mt < 2; ++mt)
#pragma unroll
        for (int nt = 0; nt < 4; ++nt)
#pragma unroll
            for (int r = 0; r < 4; ++r) {
                int row = r0 + wm * 32 + mt * 16 + crow + r;
                if (row < N)
                    Hb[(size_t)row * D + wn * 64 + nt * 16 + l15] = f2bf(acc[mt][nt][r]);
            }
}

// ---------------------------------------------------------------------------
// CSR construction: histogram -> hierarchical exclusive scan -> scatter
// ---------------------------------------------------------------------------
__global__ __launch_bounds__(256) void hist_kernel(const int* __restrict__ src,
                                                   int* __restrict__ counts, int E) {
    int i = blockIdx.x * blockDim.x + threadIdx.x;
    int stride = gridDim.x * blockDim.x;
    for (; i < E; i += stride) atomicAdd(&counts[src[i]], 1);
}

__global__ __launch_bounds__(256) void scan_partial_kernel(const int* __restrict__ counts,
                                                           int* __restrict__ blocksum, int N) {
    __shared__ int wsum[4];
    int tid = threadIdx.x;
    int i = blockIdx.x * 256 + tid;
    int x = (i < N) ? counts[i] : 0;
#pragma unroll
    for (int off = 32; off > 0; off >>= 1) x += __shfl_down(x, off);
    if ((tid & 63) == 0) wsum[tid >> 6] = x;
    __syncthreads();
    if (tid == 0) blocksum[blockIdx.x] = wsum[0] + wsum[1] + wsum[2] + wsum[3];
}

__global__ __launch_bounds__(256) void scan_top_kernel(const int* __restrict__ blocksum,
                                                       int* __restrict__ blockoff, int nblk) {
    __shared__ int wsum[4];
    int tid = threadIdx.x;
    int lane = tid & 63, w = tid >> 6;
    int v = (tid < nblk) ? blocksum[tid] : 0;
    int x = v;
#pragma unroll
    for (int off = 1; off < 64; off <<= 1) {
        int y = __shfl_up(x, off);
        if (lane >= off) x += y;
    }
    if (lane == 63) wsum[w] = x;
    __syncthreads();
    int woff = 0;
    for (int i = 0; i < w; ++i) woff += wsum[i];
    if (tid < nblk) blockoff[tid] = woff + x - v;
}

__global__ __launch_bounds__(256) void scan_final_kernel(const int* __restrict__ counts,
                                                         const int* __restrict__ blockoff,
                                                         int* __restrict__ starts,
                                                         int* __restrict__ cursor, int N) {
    __shared__ int wsum[4];
    int tid = threadIdx.x;
    int lane = tid & 63, w = tid >> 6;
    int i = blockIdx.x * 256 + tid;
    int c = (i < N) ? counts[i] : 0;
    int x = c;
#pragma unroll
    for (int off = 1; off < 64; off <<= 1) {
        int y = __shfl_up(x, off);
        if (lane >= off) x += y;
    }
    if (lane == 63) wsum[w] = x;
    __syncthreads();
    int woff = blockoff[blockIdx.x];
    for (int j = 0; j < w; ++j) woff += wsum[j];
    int pre = woff + x - c;
    if (i < N) {
        starts[i] = pre;
        cursor[i] = pre;
        if (i == N - 1) starts[N] = pre + c;
    }
}

__global__ __launch_bounds__(256) void scatter_kernel(const int* __restrict__ src,
                                                      const int* __restrict__ dst,
                                                      int* __restrict__ cursor,
                                                      int* __restrict__ dsts_sorted, int E) {
    int i = blockIdx.x * blockDim.x + threadIdx.x;
    int stride = gridDim.x * blockDim.x;
    for (; i < E; i += stride) {
        int pos = atomicAdd(&cursor[src[i]], 1);
        dsts_sorted[pos] = dst[i];
    }
}

// ---------------------------------------------------------------------------
// Node kernel: 1 block = 1 wave = 1 node. Lane l owns feature dword l
// (feats 2l, 2l+1). All edge indices are wave-uniform -> scalar loads; the
// gather is one global_load_dword with SGPR row base. Per 16-edge chunk:
// 16 gathers in flight, multi-value butterfly (stages 1..8 select, 16/32
// plain) -> every lane holds e of edge brev4(l&15); e broadcast via LDS
// (1 write + 4 uniform b128 reads). rs is lane-local (no final fold).
// ---------------------------------------------------------------------------
template <bool FULL>
__device__ __forceinline__ void process_chunk(const ushort* __restrict__ Hb,
                                              const int* __restrict__ dsts_sorted,
                                              int base, int cnt, int l,
                                              float hs0, float hs1, float2 av,
                                              int rb, bool wr, float* lds_e,
                                              float& acc0, float& acc1, float& rs) {
    uint fu[16];
#pragma unroll
    for (int j = 0; j < 16; ++j) {
        int idx = FULL ? (base + j) : (base + (j < cnt ? j : 0));
        int dj = dsts_sorted[idx];                       // wave-uniform -> s_load
        const ushort* rp = Hb + ((size_t)(uint)dj << 7); // SGPR base
        fu[j] = *(const uint*)(rp + (l << 1));
    }
    float p[16];
#pragma unroll
    for (int j = 0; j < 16; ++j) {
        float f0 = __uint_as_float(fu[j] << 16);
        float f1 = __uint_as_float(fu[j] & 0xffff0000u);
        float s0 = hs0 + f0, s1 = hs1 + f1;
        s0 = fmaxf(s0, ALPHA * s0);
        s1 = fmaxf(s1, ALPHA * s1);
        float pj = fmaf(s0, av.x, s1 * av.y);
        p[j] = (FULL || j < cnt) ? pj : -1e30f;
    }
    // butterfly multi-reduce: 16 values over 64 lanes
    {
        bool hi = l & 1;
#pragma unroll
        for (int i = 0; i < 8; ++i) {
            float send = hi ? p[i] : p[i + 8];
            float recv = __shfl_xor(send, 1);
            p[i] = (hi ? p[i + 8] : p[i]) + recv;
        }
        hi = l & 2;
#pragma unroll
        for (int i = 0; i < 4; ++i) {
            float send = hi ? p[i] : p[i + 4];
            float recv = __shfl_xor(send, 2);
            p[i] = (hi ? p[i + 4] : p[i]) + recv;
        }
        hi = l & 4;
#pragma unroll
        for (int i = 0; i < 2; ++i) {
            float send = hi ? p[i] : p[i + 2];
            float recv = __shfl_xor(send, 4);
            p[i] = (hi ? p[i + 2] : p[i]) + recv;
        }
        hi = l & 8;
        {
            float send = hi ? p[0] : p[1];
            float recv = __shfl_xor(send, 8);
            p[0] = (hi ? p[1] : p[0]) + recv;
        }
        p[0] += __shfl_xor(p[0], 16);
        p[0] += __shfl_xor(p[0], 32);
    }
    float e = __expf(p[0]);      // lane l: edge brev4(l&15)
    if (wr) lds_e[rb] = e;       // lanes 0..15 cover slots 0..15
    __syncthreads();
    float4 e0 = *(const float4*)&lds_e[0];
    float4 e1 = *(const float4*)&lds_e[4];
    float4 e2 = *(const float4*)&lds_e[8];
    float4 e3 = *(const float4*)&lds_e[12];
    __syncthreads();
    float ev[16] = {e0.x, e0.y, e0.z, e0.w, e1.x, e1.y, e1.z, e1.w,
                    e2.x, e2.y, e2.z, e2.w, e3.x, e3.y, e3.z, e3.w};
#pragma unroll
    for (int j = 0; j < 16; ++j) {
        float f0 = __uint_as_float(fu[j] << 16);
        float f1 = __uint_as_float(fu[j] & 0xffff0000u);
        acc0 = fmaf(ev[j], f0, acc0);
        acc1 = fmaf(ev[j], f1, acc1);
        rs += ev[j];
    }
}

__global__ __launch_bounds__(64) void node_kernel(const ushort* __restrict__ Hb,
                                                  const int* __restrict__ starts,
                                                  const int* __restrict__ dsts_sorted,
                                                  const float* __restrict__ a,
                                                  float* __restrict__ out, int N) {
    __shared__ __align__(16) float lds_e[16];
    const int node = blockIdx.x;
    const int l = threadIdx.x;   // 0..63

    const int beg = starts[node];
    const int end = starts[node + 1];

    const ushort* hrow = Hb + ((size_t)node << 7);
    uint hu = *(const uint*)(hrow + (l << 1));
    float hs0 = __uint_as_float(hu << 16);
    float hs1 = __uint_as_float(hu & 0xffff0000u);
    float2 av = *(const float2*)(a + (l << 1));

    const int rb = ((l & 1) << 3) | ((l & 2) << 1) | ((l & 4) >> 1) | ((l & 8) >> 3);
    const bool wr = (l < 16);

    float acc0 = 0.f, acc1 = 0.f, rs = 0.f;

    int base = beg;
    for (; base + 16 <= end; base += 16)
        process_chunk<true>(Hb, dsts_sorted, base, 16, l, hs0, hs1, av, rb, wr,
                            lds_e, acc0, acc1, rs);
    if (base < end)
        process_chunk<false>(Hb, dsts_sorted, base, end - base, l, hs0, hs1, av, rb, wr,
                             lds_e, acc0, acc1, rs);

    float inv = 1.0f / rs;
    float2 o;
    o.x = fmaxf(acc0 * inv, 0.f);
    o.y = fmaxf(acc1 * inv, 0.f);
    *(float2*)(out + ((size_t)node << 7) + (l << 1)) = o;
}

extern "C" void kernel_launch(void* const* d_in, const int* in_sizes, int n_in,
                              void* d_out, int out_size, void* d_ws, size_t ws_size,
                              hipStream_t stream) {
    const float* inputs = (const float*)d_in[0];
    const int* edge = (const int*)d_in[1];
    const float* W = (const float*)d_in[2];
    const float* a = (const float*)d_in[3];
    float* out = (float*)d_out;

    const int N = in_sizes[0] / D;   // 50000
    const int E = in_sizes[1] / 2;   // 800000

    const int* src = edge;
    const int* dst = edge + E;

    // ws layout
    ushort* wt = (ushort*)d_ws;                      // [128*128] bf16
    ushort* hb = wt + 128 * 128;                     // [N*128] bf16
    int* counts = (int*)(hb + (size_t)N * D);        // [N]
    int* starts = counts + N;                        // [N+1]
    int* cursor = starts + N + 1;                    // [N]
    int* blocksum = cursor + N;                      // [256]
    int* blockoff = blocksum + 256;                  // [256]
    int* dsts_sorted = blockoff + 256;               // [E]

    const int nblk = (N + 255) / 256;                // 196

    hipMemsetAsync(counts, 0, (size_t)N * sizeof(int), stream);

    w_prep_kernel<<<64, 256, 0, stream>>>(W, wt);
    gemm_h_kernel<<<(N + 63) / 64, 256, 0, stream>>>(inputs, wt, hb, N);
    hist_kernel<<<1024, 256, 0, stream>>>(src, counts, E);
    scan_partial_kernel<<<nblk, 256, 0, stream>>>(counts, blocksum, N);
    scan_top_kernel<<<1, 256, 0, stream>>>(blocksum, blockoff, nblk);
    scan_final_kernel<<<nblk, 256, 0, stream>>>(counts, blockoff, starts, cursor, N);
    scatter_kernel<<<1024, 256, 0, stream>>>(src, dst, cursor, dsts_sorted, E);
    node_kernel<<<N, 64, 0, stream>>>(hb, starts, dsts_sorted, a, out, N);
}

// Round 7
// 119.526 us; speedup vs baseline: 1.5790x; 1.3680x over previous
//
#include <hip/hip_runtime.h>
#include <cstdint>
#include <cstddef>

#define D 128
#define ALPHA 0.2f

typedef __attribute__((ext_vector_type(8))) short short8_t;   // 8 x bf16
typedef __attribute__((ext_vector_type(4))) float f32x4_t;

static __device__ __forceinline__ ushort f2bf(float f) {
    union { float f; uint32_t u; } v; v.f = f;
    uint32_t r = (v.u + 0x7FFFu + ((v.u >> 16) & 1u)) >> 16;
    return (ushort)r;
}

// ---------------------------------------------------------------------------
// Kernel 0: W [128][128] fp32 -> Wt [n][k] bf16 (transposed)
// ---------------------------------------------------------------------------
__global__ __launch_bounds__(256) void w_prep_kernel(const float* __restrict__ W,
                                                     ushort* __restrict__ Wt) {
    int idx = blockIdx.x * 256 + threadIdx.x;   // 0..16383
    int k = idx >> 7;
    int n = idx & 127;
    Wt[n * 128 + k] = f2bf(W[idx]);
}

// ---------------------------------------------------------------------------
// Kernel 1: Hb = bf16(A @ W) via bf16 MFMA (fp32 accum).
// ---------------------------------------------------------------------------
__global__ __launch_bounds__(256) void gemm_h_kernel(const float* __restrict__ A,
                                                     const ushort* __restrict__ Wt,
                                                     ushort* __restrict__ Hb,
                                                     int N) {
    __shared__ ushort Alds[64][136];
    const int tid = threadIdx.x;
    const int r0 = blockIdx.x * 64;

#pragma unroll
    for (int it = 0; it < 8; ++it) {
        int idx = it * 256 + tid;          // 0..2047
        int r = idx >> 5;
        int c4 = (idx & 31) * 4;
        float4 v = make_float4(0.f, 0.f, 0.f, 0.f);
        if (r0 + r < N) v = *(const float4*)(A + (size_t)(r0 + r) * D + c4);
        ushort4 b;
        b.x = f2bf(v.x); b.y = f2bf(v.y); b.z = f2bf(v.z); b.w = f2bf(v.w);
        *(ushort4*)&Alds[r][c4] = b;
    }
    __syncthreads();

    const int lane = tid & 63;
    const int w = tid >> 6;
    const int wm = w >> 1;
    const int wn = w & 1;
    const int l15 = lane & 15;
    const int koff = (lane >> 4) * 8;

    f32x4_t acc[2][4];
#pragma unroll
    for (int mt = 0; mt < 2; ++mt)
#pragma unroll
        for (int nt = 0; nt < 4; ++nt) acc[mt][nt] = (f32x4_t){0.f, 0.f, 0.f, 0.f};

    const int arow = wm * 32 + l15;
#pragma unroll
    for (int kk = 0; kk < 4; ++kk) {
        short8_t am0 = *(const short8_t*)&Alds[arow][kk * 32 + koff];
        short8_t am1 = *(const short8_t*)&Alds[arow + 16][kk * 32 + koff];
        short8_t bn[4];
#pragma unroll
        for (int nt = 0; nt < 4; ++nt)
            bn[nt] = *(const short8_t*)(Wt + (size_t)(wn * 64 + nt * 16 + l15) * 128 + kk * 32 + koff);
#pragma unroll
        for (int nt = 0; nt < 4; ++nt) {
            acc[0][nt] = __builtin_amdgcn_mfma_f32_16x16x32_bf16(am0, bn[nt], acc[0][nt], 0, 0, 0);
            acc[1][nt] = __builtin_amdgcn_mfma_f32_16x16x32_bf16(am1, bn[nt], acc[1][nt], 0, 0, 0);
        }
    }

    const int crow = (lane >> 4) * 4;
#pragma unroll
    for (int mt = 0; mt < 2; ++mt)
#pragma unroll
        for (int nt = 0; nt < 4; ++nt)
#pragma unroll
            for (int r = 0; r < 4; ++r) {
                int row = r0 + wm * 32 + mt * 16 + crow + r;
                if (row < N)
                    Hb[(size_t)row * D + wn * 64 + nt * 16 + l15] = f2bf(acc[mt][nt][r]);
            }
}

// ---------------------------------------------------------------------------
// CSR construction: hist(+rank) -> hierarchical exclusive scan -> scatter
// (scatter uses starts[src]+rank, no atomics)
// ---------------------------------------------------------------------------
__global__ __launch_bounds__(256) void hist_rank_kernel(const int* __restrict__ src,
                                                        int* __restrict__ counts,
                                                        int* __restrict__ rank, int E) {
    int i = blockIdx.x * 256 + threadIdx.x;
    if (i >= E) return;
    rank[i] = atomicAdd(&counts[src[i]], 1);
}

__global__ __launch_bounds__(256) void scan_partial_kernel(const int* __restrict__ counts,
                                                           int* __restrict__ blocksum, int N) {
    __shared__ int wsum[4];
    int tid = threadIdx.x;
    int i = blockIdx.x * 256 + tid;
    int x = (i < N) ? counts[i] : 0;
#pragma unroll
    for (int off = 32; off > 0; off >>= 1) x += __shfl_down(x, off);
    if ((tid & 63) == 0) wsum[tid >> 6] = x;
    __syncthreads();
    if (tid == 0) blocksum[blockIdx.x] = wsum[0] + wsum[1] + wsum[2] + wsum[3];
}

__global__ __launch_bounds__(256) void scan_top_kernel(const int* __restrict__ blocksum,
                                                       int* __restrict__ blockoff, int nblk) {
    __shared__ int wsum[4];
    int tid = threadIdx.x;
    int lane = tid & 63, w = tid >> 6;
    int v = (tid < nblk) ? blocksum[tid] : 0;
    int x = v;
#pragma unroll
    for (int off = 1; off < 64; off <<= 1) {
        int y = __shfl_up(x, off);
        if (lane >= off) x += y;
    }
    if (lane == 63) wsum[w] = x;
    __syncthreads();
    int woff = 0;
    for (int i = 0; i < w; ++i) woff += wsum[i];
    if (tid < nblk) blockoff[tid] = woff + x - v;
}

__global__ __launch_bounds__(256) void scan_final_kernel(const int* __restrict__ counts,
                                                         const int* __restrict__ blockoff,
                                                         int* __restrict__ starts, int N) {
    __shared__ int wsum[4];
    int tid = threadIdx.x;
    int lane = tid & 63, w = tid >> 6;
    int i = blockIdx.x * 256 + tid;
    int c = (i < N) ? counts[i] : 0;
    int x = c;
#pragma unroll
    for (int off = 1; off < 64; off <<= 1) {
        int y = __shfl_up(x, off);
        if (lane >= off) x += y;
    }
    if (lane == 63) wsum[w] = x;
    __syncthreads();
    int woff = blockoff[blockIdx.x];
    for (int j = 0; j < w; ++j) woff += wsum[j];
    int pre = woff + x - c;
    if (i < N) {
        starts[i] = pre;
        if (i == N - 1) starts[N] = pre + c;
    }
}

__global__ __launch_bounds__(256) void scatter_kernel(const int* __restrict__ src,
                                                      const int* __restrict__ dst,
                                                      const int* __restrict__ rank,
                                                      const int* __restrict__ starts,
                                                      int* __restrict__ dsts_sorted, int E) {
    int i = blockIdx.x * 256 + threadIdx.x;
    if (i >= E) return;
    int pos = starts[src[i]] + rank[i];
    dsts_sorted[pos] = dst[i];
}

// ---------------------------------------------------------------------------
// Node kernel: 1 block = 1 wave = 1 node. Lane l owns feature dword l.
// All edge indices wave-uniform -> scalar loads; gather = 1 dword with SGPR
// base. 16-edge chunks: butterfly multi-reduce, e broadcast via LDS.
// ---------------------------------------------------------------------------
template <bool FULL>
__device__ __forceinline__ void process_chunk(const ushort* __restrict__ Hb,
                                              const int* __restrict__ dsts_sorted,
                                              int base, int cnt, int l,
                                              float hs0, float hs1, float2 av,
                                              int rb, bool wr, float* lds_e,
                                              float& acc0, float& acc1, float& rs) {
    uint fu[16];
#pragma unroll
    for (int j = 0; j < 16; ++j) {
        int idx = FULL ? (base + j) : (base + (j < cnt ? j : 0));
        int dj = dsts_sorted[idx];                       // wave-uniform -> s_load
        const ushort* rp = Hb + ((size_t)(uint)dj << 7); // SGPR base
        fu[j] = *(const uint*)(rp + (l << 1));
    }
    float p[16];
#pragma unroll
    for (int j = 0; j < 16; ++j) {
        float f0 = __uint_as_float(fu[j] << 16);
        float f1 = __uint_as_float(fu[j] & 0xffff0000u);
        float s0 = hs0 + f0, s1 = hs1 + f1;
        s0 = fmaxf(s0, ALPHA * s0);
        s1 = fmaxf(s1, ALPHA * s1);
        float pj = fmaf(s0, av.x, s1 * av.y);
        p[j] = (FULL || j < cnt) ? pj : -1e30f;
    }
    {
        bool hi = l & 1;
#pragma unroll
        for (int i = 0; i < 8; ++i) {
            float send = hi ? p[i] : p[i + 8];
            float recv = __shfl_xor(send, 1);
            p[i] = (hi ? p[i + 8] : p[i]) + recv;
        }
        hi = l & 2;
#pragma unroll
        for (int i = 0; i < 4; ++i) {
            float send = hi ? p[i] : p[i + 4];
            float recv = __shfl_xor(send, 2);
            p[i] = (hi ? p[i + 4] : p[i]) + recv;
        }
        hi = l & 4;
#pragma unroll
        for (int i = 0; i < 2; ++i) {
            float send = hi ? p[i] : p[i + 2];
            float recv = __shfl_xor(send, 4);
            p[i] = (hi ? p[i + 2] : p[i]) + recv;
        }
        hi = l & 8;
        {
            float send = hi ? p[0] : p[1];
            float recv = __shfl_xor(send, 8);
            p[0] = (hi ? p[1] : p[0]) + recv;
        }
        p[0] += __shfl_xor(p[0], 16);
        p[0] += __shfl_xor(p[0], 32);
    }
    float e = __expf(p[0]);      // lane l: edge brev4(l&15)
    if (wr) lds_e[rb] = e;       // lanes 0..15 cover slots 0..15
    __syncthreads();
    float4 e0 = *(const float4*)&lds_e[0];
    float4 e1 = *(const float4*)&lds_e[4];
    float4 e2 = *(const float4*)&lds_e[8];
    float4 e3 = *(const float4*)&lds_e[12];
    __syncthreads();
    float ev[16] = {e0.x, e0.y, e0.z, e0.w, e1.x, e1.y, e1.z, e1.w,
                    e2.x, e2.y, e2.z, e2.w, e3.x, e3.y, e3.z, e3.w};
#pragma unroll
    for (int j = 0; j < 16; ++j) {
        float f0 = __uint_as_float(fu[j] << 16);
        float f1 = __uint_as_float(fu[j] & 0xffff0000u);
        acc0 = fmaf(ev[j], f0, acc0);
        acc1 = fmaf(ev[j], f1, acc1);
        rs += ev[j];
    }
}

__global__ __launch_bounds__(64) void node_kernel(const ushort* __restrict__ Hb,
                                                  const int* __restrict__ starts,
                                                  const int* __restrict__ dsts_sorted,
                                                  const float* __restrict__ a,
                                                  float* __restrict__ out, int N) {
    __shared__ __align__(16) float lds_e[16];
    const int node = blockIdx.x;
    const int l = threadIdx.x;   // 0..63

    const int beg = starts[node];
    const int end = starts[node + 1];

    const ushort* hrow = Hb + ((size_t)node << 7);
    uint hu = *(const uint*)(hrow + (l << 1));
    float hs0 = __uint_as_float(hu << 16);
    float hs1 = __uint_as_float(hu & 0xffff0000u);
    float2 av = *(const float2*)(a + (l << 1));

    const int rb = ((l & 1) << 3) | ((l & 2) << 1) | ((l & 4) >> 1) | ((l & 8) >> 3);
    const bool wr = (l < 16);

    float acc0 = 0.f, acc1 = 0.f, rs = 0.f;

    int base = beg;
    for (; base + 16 <= end; base += 16)
        process_chunk<true>(Hb, dsts_sorted, base, 16, l, hs0, hs1, av, rb, wr,
                            lds_e, acc0, acc1, rs);
    if (base < end)
        process_chunk<false>(Hb, dsts_sorted, base, end - base, l, hs0, hs1, av, rb, wr,
                             lds_e, acc0, acc1, rs);

    float inv = 1.0f / rs;
    float2 o;
    o.x = fmaxf(acc0 * inv, 0.f);
    o.y = fmaxf(acc1 * inv, 0.f);
    *(float2*)(out + ((size_t)node << 7) + (l << 1)) = o;
}

extern "C" void kernel_launch(void* const* d_in, const int* in_sizes, int n_in,
                              void* d_out, int out_size, void* d_ws, size_t ws_size,
                              hipStream_t stream) {
    const float* inputs = (const float*)d_in[0];
    const int* edge = (const int*)d_in[1];
    const float* W = (const float*)d_in[2];
    const float* a = (const float*)d_in[3];
    float* out = (float*)d_out;

    const int N = in_sizes[0] / D;   // 50000
    const int E = in_sizes[1] / 2;   // 800000

    const int* src = edge;
    const int* dst = edge + E;

    // ws layout
    ushort* wt = (ushort*)d_ws;                      // [128*128] bf16
    ushort* hb = wt + 128 * 128;                     // [N*128] bf16
    int* counts = (int*)(hb + (size_t)N * D);        // [N]
    int* starts = counts + N;                        // [N+1]
    int* blocksum = starts + N + 1;                  // [256]
    int* blockoff = blocksum + 256;                  // [256]
    int* rank = blockoff + 256;                      // [E]
    int* dsts_sorted = rank + E;                     // [E]

    const int nblk = (N + 255) / 256;                // 196
    const int eblk = (E + 255) / 256;                // 3125

    hipMemsetAsync(counts, 0, (size_t)N * sizeof(int), stream);

    w_prep_kernel<<<64, 256, 0, stream>>>(W, wt);
    gemm_h_kernel<<<(N + 63) / 64, 256, 0, stream>>>(inputs, wt, hb, N);
    hist_rank_kernel<<<eblk, 256, 0, stream>>>(src, counts, rank, E);
    scan_partial_kernel<<<nblk, 256, 0, stream>>>(counts, blocksum, N);
    scan_top_kernel<<<1, 256, 0, stream>>>(blocksum, blockoff, nblk);
    scan_final_kernel<<<nblk, 256, 0, stream>>>(counts, blockoff, starts, N);
    scatter_kernel<<<eblk, 256, 0, stream>>>(src, dst, rank, starts, dsts_sorted, E);
    node_kernel<<<N, 64, 0, stream>>>(hb, starts, dsts_sorted, a, out, N);
}